// Round 1
// baseline (314.688 us; speedup 1.0000x reference)
//
#include <hip/hip_runtime.h>

// YOLO layer loss, MI355X. Shapes fixed by the reference:
// B=16, GH=GW=64, NA=3, NC=80, T=100, net=1024.
// y_pred  : contiguous (196608, 85) fp32
// y_true  : contiguous (196608, 85) fp32
// true_boxes: (16, 100, 4) fp32
// out: 16 fp32 (per-batch loss)

#define GH 64
#define GW 64
#define NA 3
#define NC 80
#define NT 100
#define CPB (GH * GW * NA)   // 12288 cell-anchors per batch
#define NTOT (16 * CPB)      // 196608

__device__ __forceinline__ float frcp(float x) { return __builtin_amdgcn_rcpf(x); }
__device__ __forceinline__ float fsig(float x) { return frcp(1.f + __expf(-x)); }

__global__ __launch_bounds__(256) void yolo_loss_kernel(
    const float* __restrict__ y_pred,
    const float* __restrict__ y_true,
    const float* __restrict__ true_boxes,
    float* __restrict__ out)
{
    __shared__ float4 sbox[NT];   // (min_x, min_y, max_x, max_y)
    __shared__ float  sarea[NT];
    __shared__ float  swsum[4];

    const int tid = threadIdx.x;
    const int idx = blockIdx.x * 256 + tid;   // cell-anchor id
    const int b   = idx / CPB;                // block-uniform (12288 % 256 == 0)

    // Stage per-batch true boxes: precompute mins/maxes/area. 2.4 KB LDS.
    if (tid < NT) {
        const float4 tb = *(const float4*)(true_boxes + (size_t)b * NT * 4 + tid * 4);
        float tx = tb.x * (1.f / GW),     ty = tb.y * (1.f / GH);
        float tw = tb.z * (1.f / 1024.f), th = tb.w * (1.f / 1024.f);
        sbox[tid]  = make_float4(tx - 0.5f * tw, ty - 0.5f * th,
                                 tx + 0.5f * tw, ty + 0.5f * th);
        sarea[tid] = tw * th;
    }
    __syncthreads();

    const int rem = idx % CPB;
    const int gy  = rem / (GW * NA);
    const int r2  = rem - gy * (GW * NA);
    const int gx  = r2 / NA;
    const int a   = r2 - gx * NA;

    const float aw = (a == 0) ? 116.f : ((a == 1) ? 156.f : 373.f);
    const float ah = (a == 0) ? 90.f  : ((a == 1) ? 198.f : 326.f);

    const float* p = y_pred + (size_t)idx * 85;
    const float* t = y_true + (size_t)idx * 85;

    const float p0 = p[0], p1 = p[1], p2 = p[2], p3 = p[3], p4 = p[4];
    const float t0 = t[0], t1 = t[1], t2 = t[2], t3 = t[3], om = t[4];

    // Class logits register-resident: lets the compiler batch 80 loads.
    float pc[NC];
#pragma unroll
    for (int j = 0; j < NC; ++j) pc[j] = p[5 + j];

    float m = pc[0];
#pragma unroll
    for (int j = 1; j < NC; ++j) m = fmaxf(m, pc[j]);
    float s = 0.f;
#pragma unroll
    for (int j = 0; j < NC; ++j) s += __expf(pc[j] - m);
    const float lse = m + __logf(s);

    // argmax(y_true classes) fused with select of pc[argmax] (first-max wins).
    float tmax = -1.f, psel = 0.f;
#pragma unroll
    for (int j = 0; j < NC; ++j) {
        const float tj = t[5 + j];
        const bool g = tj > tmax;
        tmax = g ? tj : tmax;
        psel = g ? pc[j] : psel;
    }
    const float ce = lse - psel;   // -log_softmax at true class

    const float predx = (float)gx + fsig(p0);
    const float predy = (float)gy + fsig(p1);
    const float conf  = fsig(p4);
    const float pw = __expf(p2) * aw * (1.f / 1024.f);
    const float ph = __expf(p3) * ah * (1.f / 1024.f);
    const float parea = pw * ph;
    const float px = predx * (1.f / GW), py = predy * (1.f / GH);
    const float pminx = px - 0.5f * pw, pmaxx = px + 0.5f * pw;
    const float pminy = py - 0.5f * ph, pmaxy = py + 0.5f * ph;

    float best = 0.f;   // iou >= 0 always
#pragma unroll 4
    for (int ti = 0; ti < NT; ++ti) {
        const float4 bx = sbox[ti];           // broadcast: conflict-free
        float iw = fminf(pmaxx, bx.z) - fmaxf(pminx, bx.x);
        float ih = fminf(pmaxy, bx.w) - fmaxf(pminy, bx.y);
        iw = fmaxf(iw, 0.f); ih = fmaxf(ih, 0.f);
        const float inter = iw * ih;
        const float iou = inter * frcp(parea + sarea[ti] - inter);
        best = fmaxf(best, iou);
    }
    const float ignore = (best > 0.5f) ? 1.f : 0.f;

    const float wsx = __expf(t2) * aw * (1.f / 1024.f);
    const float wsy = __expf(t3) * ah * (1.f / 1024.f);
    const float ws  = 2.f - wsx * wsy;
    const float omws = om * ws;

    const float dx = omws * (t0 - predx);
    const float dy = omws * (t1 - predy);
    const float dw = omws * (t2 - p2);
    const float dh = omws * (t3 - p3);
    float dc = -conf + om * (1.f - conf) * 5.f;
    dc *= (1.f - (1.f - om) * ignore);
    const float dcl = om * ce;

    float val = dx * dx + dy * dy + dw * dw + dh * dh + dc * dc + dcl * dcl;

    // wave reduce (width 64), then block reduce via LDS, one atomic per block
#pragma unroll
    for (int off = 32; off > 0; off >>= 1) val += __shfl_down(val, off, 64);
    if ((tid & 63) == 0) swsum[tid >> 6] = val;
    __syncthreads();
    if (tid == 0) atomicAdd(out + b, swsum[0] + swsum[1] + swsum[2] + swsum[3]);
}

extern "C" void kernel_launch(void* const* d_in, const int* in_sizes, int n_in,
                              void* d_out, int out_size, void* d_ws, size_t ws_size,
                              hipStream_t stream) {
    // inputs: [0]=input_image (unused, shape-only), [1]=y_pred, [2]=y_true, [3]=true_boxes
    const float* y_pred     = (const float*)d_in[1];
    const float* y_true     = (const float*)d_in[2];
    const float* true_boxes = (const float*)d_in[3];
    float* out = (float*)d_out;

    hipMemsetAsync(d_out, 0, (size_t)out_size * sizeof(float), stream);
    yolo_loss_kernel<<<NTOT / 256, 256, 0, stream>>>(y_pred, y_true, true_boxes, out);
}